// Round 3
// baseline (743.832 us; speedup 1.0000x reference)
//
#include <hip/hip_runtime.h>
#include <hip/hip_fp16.h>
#include <stdint.h>
#include <stddef.h>

#define NLVL 16
#define NLG 8                // levels per enc kernel
#define TABROWS 16384
#define BLK 512              // threads per block
#define PPT 4                // points per thread
#define PPB (BLK * PPT)      // 2048 points per block
#define NBLK (1048576 / PPB) // 512 blocks
#define TSCALE 8192.0f       // 2^13: keeps |emb|*scale in fp16-normal range
#define TINV   (1.0f / 8192.0f)

constexpr int RES_[NLVL]  = {16,20,25,32,40,50,64,80,101,128,161,203,256,322,406,512};
// staged bytes per level (4 B/entry fp16x2), rounded up to 16
constexpr int NBYTES_[NLVL] = {16384,32000,62512,65536,65536,65536,65536,65536,
                               65536,65536,65536,65536,65536,65536,65536,65536};

typedef __attribute__((address_space(1))) void gv_t;
typedef __attribute__((address_space(3))) void lv_t;

// ---- kernel 1: convert fp32 tables -> scaled fp16x2 in workspace (1 MiB) ----
__global__ __launch_bounds__(256) void cvt_tab(const float* __restrict__ src,
                                               uint32_t* __restrict__ dst) {
    int i = blockIdx.x * 256 + threadIdx.x;          // 131072 threads, 4 floats each
    float4 v = ((const float4*)src)[i];
    __half2 a = __floats2half2_rn(v.x * TSCALE, v.y * TSCALE);
    __half2 b = __floats2half2_rn(v.z * TSCALE, v.w * TSCALE);
    uint2 o;
    o.x = *(uint32_t*)&a;
    o.y = *(uint32_t*)&b;
    ((uint2*)dst)[i] = o;
}

// ---- kernel 2: encode 8 levels [LBASE, LBASE+8). 4 points/thread.
//      Single 64-KiB LDS buffer -> 2 blocks/CU co-resident: one block's
//      barrier/stage drain overlaps the other block's compute. ----
template<int LBASE>
__global__ __launch_bounds__(BLK, 4) void enc(const float* __restrict__ x,
                                              const uint32_t* __restrict__ tab,
                                              float* __restrict__ out) {
    __shared__ uint32_t lds[TABROWS];                // 64 KiB
    const int tid = threadIdx.x;
    const int pbase = blockIdx.x * PPB + tid;

    // load 4 points' coords (consecutive points within each 512-chunk -> coalesced)
    float pc[PPT][3];
#pragma unroll
    for (int j = 0; j < PPT; ++j) {
        const int p = pbase + j * BLK;
        pc[j][0] = x[3*p + 0];
        pc[j][1] = x[3*p + 1];
        pc[j][2] = x[3*p + 2];
    }

    float acc[PPT][2 * NLG];                         // 64 fp32 -> VGPRs (cap 128)

#pragma unroll
    for (int i = 0; i < NLG; ++i) {
        const int lvl = LBASE + i;

        // wait until all waves finished gathering from the previous level
        __syncthreads();

        // async-stage this level's table into LDS
        {
            const int nb = NBYTES_[lvl];
            const char* g = (const char*)tab + (size_t)lvl * TABROWS * 4;
            char* l = (char*)&lds[0];
#pragma unroll
            for (int base = 0; base < nb; base += BLK * 16) {
                int o = base + tid * 16;
                if (o < nb)
                    __builtin_amdgcn_global_load_lds((gv_t*)(g + o), (lv_t*)(l + o), 16, 0, 0);
            }
        }

        // drain stage (vmcnt0) + barrier: table now visible to all waves
        __syncthreads();

        const int r = RES_[lvl];
        const bool hashing = (lvl >= 3);
        const float rh = 0.5f * (float)r;            // exact (pow2 * small int)
        const uint32_t PRIME[3]  = {1u, 2654435761u, 805459861u};
        const uint32_t STRIDE[3] = {1u, (uint32_t)r, (uint32_t)(r * r)};

#pragma unroll
        for (int j = 0; j < PPT; ++j) {
            uint32_t t[3][2];
            float w[3][2];
#pragma unroll
            for (int d = 0; d < 3; ++d) {
                // ((x+1)*res)*0.5 - 0.5 == (x+1)*(res*0.5) - 0.5 (pow2 exact)
                float xs = (pc[j][d] + 1.0f) * rh - 0.5f;
                float fl = floorf(xs);
                float xf = xs - fl;
                int xi = (int)fl;
                bool v0 = (xi >= 0) && (xi < r);
                bool v1 = (xi >= -1) && (xi < r - 1);
                w[d][0] = v0 ? (1.0f - xf) : 0.0f;   // validity folded into weights
                w[d][1] = v1 ? xf : 0.0f;
                if (hashing) {
                    t[d][0] = (uint32_t)xi * PRIME[d]; // uint32 wrap == ref semantics
                    t[d][1] = t[d][0] + PRIME[d];      // (xi+1)*P mod 2^32
                } else {
                    // zeroed invalid contributions keep idx in [0, r^3), no mod
                    t[d][0] = v0 ? (uint32_t)xi * STRIDE[d] : 0u;
                    t[d][1] = v1 ? (uint32_t)(xi + 1) * STRIDE[d] : 0u;
                }
            }

            float a0 = 0.0f, a1 = 0.0f;
#pragma unroll
            for (int o0 = 0; o0 < 2; ++o0) {
#pragma unroll
                for (int o1 = 0; o1 < 2; ++o1) {
                    uint32_t q01 = hashing ? (t[0][o0] ^ t[1][o1]) : (t[0][o0] + t[1][o1]);
                    float w01 = w[0][o0] * w[1][o1];
#pragma unroll
                    for (int o2 = 0; o2 < 2; ++o2) {
                        uint32_t idx = hashing ? ((q01 ^ t[2][o2]) & 16383u)
                                               : (q01 + t[2][o2]);
                        float wc = w01 * w[2][o2];
                        uint32_t pk = lds[idx];      // ds_read_b32: fp16x2 entry
                        __half2 h = *(__half2*)&pk;
                        a0 = fmaf(wc, __low2float(h), a0);   // v_fma_mix
                        a1 = fmaf(wc, __high2float(h), a1);
                    }
                }
            }
            acc[j][2 * i + 0] = a0;
            acc[j][2 * i + 1] = a1;
        }
    }

    // epilogue: per point one 64-B half line, 4 x float4 (undo table scale)
#pragma unroll
    for (int j = 0; j < PPT; ++j) {
        const int p = pbase + j * BLK;
        float4* o4 = (float4*)(out + (size_t)p * (2 * NLVL) + 2 * LBASE);
#pragma unroll
        for (int k = 0; k < (2 * NLG) / 4; ++k)
            o4[k] = make_float4(acc[j][4*k + 0] * TINV, acc[j][4*k + 1] * TINV,
                                acc[j][4*k + 2] * TINV, acc[j][4*k + 3] * TINV);
    }
}

extern "C" void kernel_launch(void* const* d_in, const int* in_sizes, int n_in,
                              void* d_out, int out_size, void* d_ws, size_t ws_size,
                              hipStream_t stream) {
    const float* x   = (const float*)d_in[0];   // (B, 3) fp32
    const float* emb = (const float*)d_in[1];   // (16, 16384, 2) fp32
    float* out = (float*)d_out;                 // (B, 16, 2) fp32
    uint32_t* tab = (uint32_t*)d_ws;            // 16*16384 fp16x2 = 1 MiB scratch

    cvt_tab<<<512, 256, 0, stream>>>(emb, tab);
    enc<0><<<NBLK, BLK, 0, stream>>>(x, tab, out);
    enc<8><<<NBLK, BLK, 0, stream>>>(x, tab, out);
}

// Round 4
// 520.803 us; speedup vs baseline: 1.4282x; 1.4282x over previous
//
#include <hip/hip_runtime.h>
#include <hip/hip_fp16.h>
#include <stdint.h>
#include <stddef.h>

#define NLVL 16
#define NLG 8                // levels per group
#define TABROWS 16384
#define BLK 512              // threads per block
#define PPT 4                // points per thread
#define PPB (BLK * PPT)      // 2048 points per block-instance
#define NCHUNK (1048576 / PPB) // 512 point-chunks; x2 groups -> 1024 blocks
#define TSCALE 8192.0f       // 2^13: keeps |emb|*scale in fp16-normal range
#define TINV   (1.0f / 8192.0f)

constexpr int RES_[NLVL]  = {16,20,25,32,40,50,64,80,101,128,161,203,256,322,406,512};
// staged bytes per level (4 B/entry fp16x2), rounded up to 16
constexpr int NBYTES_[NLVL] = {16384,32000,62512,65536,65536,65536,65536,65536,
                               65536,65536,65536,65536,65536,65536,65536,65536};

typedef __attribute__((address_space(1))) void gv_t;
typedef __attribute__((address_space(3))) void lv_t;

// ---- kernel 1: convert fp32 tables -> scaled fp16x2 in workspace (1 MiB) ----
__global__ __launch_bounds__(256) void cvt_tab(const float* __restrict__ src,
                                               uint32_t* __restrict__ dst) {
    int i = blockIdx.x * 256 + threadIdx.x;          // 131072 threads, 4 floats each
    float4 v = ((const float4*)src)[i];
    __half2 a = __floats2half2_rn(v.x * TSCALE, v.y * TSCALE);
    __half2 b = __floats2half2_rn(v.z * TSCALE, v.w * TSCALE);
    uint2 o;
    o.x = *(uint32_t*)&a;
    o.y = *(uint32_t*)&b;
    ((uint2*)dst)[i] = o;
}

// ---- encode 8 levels [LBASE, LBASE+8) for 2048 points. 4 points/thread.
//      acc packed as fp16x2 per level (32 VGPRs) to stay under the 128-VGPR
//      cap of __launch_bounds__(512,2) -> 2 blocks/CU with the 64-KiB buffer,
//      so one block's stage/drain overlaps the other's compute. ----
template<int LBASE>
__device__ __forceinline__ void enc_body(int chunk, const float* __restrict__ x,
                                         const uint32_t* __restrict__ tab,
                                         float* __restrict__ out,
                                         uint32_t* __restrict__ lds) {
    const int tid = threadIdx.x;
    const int pbase = chunk * PPB + tid;

    float pc[PPT][3];
#pragma unroll
    for (int j = 0; j < PPT; ++j) {
        const int p = pbase + j * BLK;
        pc[j][0] = x[3*p + 0];
        pc[j][1] = x[3*p + 1];
        pc[j][2] = x[3*p + 2];
    }

    uint32_t acc[PPT][NLG];                          // fp16x2-packed per level

#pragma unroll
    for (int i = 0; i < NLG; ++i) {
        const int lvl = LBASE + i;

        // all waves of this block done gathering from the previous level
        __syncthreads();

        // async-stage this level's table into LDS
        {
            const int nb = NBYTES_[lvl];
            const char* g = (const char*)tab + (size_t)lvl * TABROWS * 4;
            char* l = (char*)lds;
#pragma unroll
            for (int base = 0; base < nb; base += BLK * 16) {
                int o = base + tid * 16;
                if (o < nb)
                    __builtin_amdgcn_global_load_lds((gv_t*)(g + o), (lv_t*)(l + o), 16, 0, 0);
            }
        }

        // drain stage (vmcnt0) + barrier: table now visible to all waves
        __syncthreads();

        const int r = RES_[lvl];
        const bool hashing = (lvl >= 3);
        const float rh = 0.5f * (float)r;            // exact (pow2 * small int)
        const uint32_t PRIME[3]  = {1u, 2654435761u, 805459861u};
        const uint32_t STRIDE[3] = {1u, (uint32_t)r, (uint32_t)(r * r)};

#pragma unroll
        for (int j = 0; j < PPT; ++j) {
            uint32_t t[3][2];
            float w[3][2];
#pragma unroll
            for (int d = 0; d < 3; ++d) {
                // ((x+1)*res)*0.5 - 0.5 == (x+1)*(res*0.5) - 0.5 (pow2 exact)
                float xs = (pc[j][d] + 1.0f) * rh - 0.5f;
                float fl = floorf(xs);
                float xf = xs - fl;
                int xi = (int)fl;
                bool v0 = (xi >= 0) && (xi < r);
                bool v1 = (xi >= -1) && (xi < r - 1);
                w[d][0] = v0 ? (1.0f - xf) : 0.0f;   // validity folded into weights
                w[d][1] = v1 ? xf : 0.0f;
                if (hashing) {
                    t[d][0] = (uint32_t)xi * PRIME[d]; // uint32 wrap == ref semantics
                    t[d][1] = t[d][0] + PRIME[d];      // (xi+1)*P mod 2^32
                } else {
                    // zeroed invalid contributions keep idx in [0, r^3), no mod
                    t[d][0] = v0 ? (uint32_t)xi * STRIDE[d] : 0u;
                    t[d][1] = v1 ? (uint32_t)(xi + 1) * STRIDE[d] : 0u;
                }
            }

            float a0 = 0.0f, a1 = 0.0f;
#pragma unroll
            for (int o0 = 0; o0 < 2; ++o0) {
#pragma unroll
                for (int o1 = 0; o1 < 2; ++o1) {
                    uint32_t q01 = hashing ? (t[0][o0] ^ t[1][o1]) : (t[0][o0] + t[1][o1]);
                    float w01 = w[0][o0] * w[1][o1];
#pragma unroll
                    for (int o2 = 0; o2 < 2; ++o2) {
                        uint32_t idx = hashing ? ((q01 ^ t[2][o2]) & 16383u)
                                               : (q01 + t[2][o2]);
                        float wc = w01 * w[2][o2];
                        uint32_t pk = lds[idx];      // ds_read_b32: fp16x2 entry
                        __half2 h = *(__half2*)&pk;
                        a0 = fmaf(wc, __low2float(h), a0);
                        a1 = fmaf(wc, __high2float(h), a1);
                    }
                }
            }
            // pack finished level result to fp16x2 (one v_cvt_pkrtz_f16_f32);
            // adds <=5e-8 abs error in unscaled domain -- 4x margin kept
            __half2 hp = __floats2half2_rn(a0, a1);
            acc[j][i] = *(uint32_t*)&hp;
        }
    }

    // epilogue: per point one 64-B half line, 4 x float4 (unpack, undo scale)
#pragma unroll
    for (int j = 0; j < PPT; ++j) {
        const int p = pbase + j * BLK;
        float4* o4 = (float4*)(out + (size_t)p * (2 * NLVL) + 2 * LBASE);
#pragma unroll
        for (int k = 0; k < NLG / 2; ++k) {
            __half2 h0 = *(__half2*)&acc[j][2*k + 0];
            __half2 h1 = *(__half2*)&acc[j][2*k + 1];
            o4[k] = make_float4(__low2float(h0) * TINV, __high2float(h0) * TINV,
                                __low2float(h1) * TINV, __high2float(h1) * TINV);
        }
    }
}

// one dispatch, 1024 blocks: group = bx&1 (levels 0-7 vs 8-15), chunk = bx>>1.
// Adjacent blocks are in different groups -> co-resident blocks on a CU tend
// to be phase-decorrelated (one computes while the other drains its stage).
__global__ __launch_bounds__(BLK, 2) void enc(const float* __restrict__ x,
                                              const uint32_t* __restrict__ tab,
                                              float* __restrict__ out) {
    __shared__ uint32_t lds[TABROWS];                // 64 KiB -> 2 blocks/CU
    const int chunk = blockIdx.x >> 1;
    if ((blockIdx.x & 1) == 0) enc_body<0>(chunk, x, tab, out, lds);
    else                       enc_body<8>(chunk, x, tab, out, lds);
}

extern "C" void kernel_launch(void* const* d_in, const int* in_sizes, int n_in,
                              void* d_out, int out_size, void* d_ws, size_t ws_size,
                              hipStream_t stream) {
    const float* x   = (const float*)d_in[0];   // (B, 3) fp32
    const float* emb = (const float*)d_in[1];   // (16, 16384, 2) fp32
    float* out = (float*)d_out;                 // (B, 16, 2) fp32
    uint32_t* tab = (uint32_t*)d_ws;            // 16*16384 fp16x2 = 1 MiB scratch

    cvt_tab<<<512, 256, 0, stream>>>(emb, tab);
    enc<<<2 * NCHUNK, BLK, 0, stream>>>(x, tab, out);
}